// Round 4
// baseline (226.928 us; speedup 1.0000x reference)
//
#include <hip/hip_runtime.h>
#include <stdint.h>

// Problem: B=4, L=2048, DM=1024, N=64.
//   y[b,t,m] = D[m]*x[b,t,m] + sum_u K[b,u,m]*x[b,t-u,m]
//   K[b,u,m] = sum_n C[n,m] * A_n^u * (x[b,u,:]·W_B[n,:] + b_B[n]), A_n = e^{0.1-(3n+1)}
// A_n^u support (verified R2, absmax 0.0625): 80 (u,n) dots total, taps u>=8 zero.
//
// R4: SINGLE launch. blockIdx.x==0 blocks (2 per batch) compute the 80 dots and
// publish gl[b][80] via AGENT-scope atomics + magic-word release; all blocks
// issue their conv x-loads FIRST (HBM stream starts immediately), consumers
// spin ~1us, rebuild their 8 K-taps from gl·C (L2-hot), then run the R3
// register-window FIR. Deadlock-free: launch_bounds(256,4) => <=128 VGPR =>
// >=4 blocks/CU => 1024 resident slots >= 512 grid (all blocks co-resident).
// Magic 0x5A5AF00D1234BEEF: hi!=lo (uniform-u32 poison can't match) and hi32
// as a float is ~1.5e16 (unreachable by stale O(1) float garbage).

#define BATCH 4
#define SEQ_L 2048
#define DMODEL 1024
#define NSTATE 64
#define T_TAP 8
#define HALO (T_TAP - 1)  // 7
#define TT 32             // t-outputs per thread
#define NPAIR 16
#define NGL (NSTATE + NPAIR)  // 80
#define MAGIC 0x5A5AF00D1234BEEFULL

__device__ __forceinline__ void pair_un(int p, int& u, int& n) {
  if (p < 6)       { u = 1; n = p; }
  else if (p < 9)  { u = 2; n = p - 6; }
  else if (p < 11) { u = 3; n = p - 9; }
  else             { u = (p < 13) ? 4 : p - 8; n = (p < 13) ? (p - 11) : 0; }
}

// grid = (L/TT=64, DM/512=2, B=4) = 512 blocks x 256 thr.
__global__ __launch_bounds__(256, 4) void s4_one(
    const float* __restrict__ x, const float* __restrict__ W_B,
    const float* __restrict__ b_B, const float* __restrict__ C,
    const float* __restrict__ D, const float* __restrict__ log_A,
    float* __restrict__ y, float* __restrict__ ws) {
  const int tid = threadIdx.x;
  const int t0 = blockIdx.x * TT;
  const int m2 = blockIdx.y * 256 + tid;  // float2-channel index 0..511
  const int b = blockIdx.z;
  const int S2 = DMODEL / 2;

  float* glp = ws + (size_t)b * 128;                                  // 80 floats
  uint64_t* mg = (uint64_t*)((char*)ws + 4096 + (size_t)b * 128);     // magic

  __shared__ float gls[NGL];
  const bool producer = (blockIdx.x == 0);

  // ---- Everyone: issue conv x-window loads first (stream starts at t=0) ----
  const float2* x2 = (const float2*)(x + (size_t)b * SEQ_L * DMODEL) + m2;
  float2 xr[TT + HALO];
#pragma unroll
  for (int i = 0; i < HALO; ++i) {
    const int t = t0 - HALO + i;
    xr[i] = (t >= 0) ? x2[(size_t)t * S2] : make_float2(0.f, 0.f);
  }
#pragma unroll
  for (int j = 0; j < TT; ++j) xr[HALO + j] = x2[(size_t)(t0 + j) * S2];
  const float2 d2 = *(const float2*)(D + 2 * m2);

  if (producer) {
    // ---- 80 dots (R2's verified decomposition), x-loads still in flight ----
    __shared__ float glr[NGL];
    {  // u=0, all 64 n: 4 threads per n-row, 2 ILP chains
      const int n = tid >> 2, s4 = tid & 3;
      const float4* xw = (const float4*)(x + (size_t)b * SEQ_L * DMODEL);
      const float4* wr = (const float4*)(W_B + (size_t)n * DMODEL);
      float s0 = 0.f, s1 = 0.f;
#pragma unroll
      for (int k = 0; k < 64; k += 2) {
        const float4 xa = xw[k * 4 + s4],       wa = wr[k * 4 + s4];
        const float4 xb = xw[(k + 1) * 4 + s4], wb = wr[(k + 1) * 4 + s4];
        s0 += xa.x * wa.x + xa.y * wa.y + xa.z * wa.z + xa.w * wa.w;
        s1 += xb.x * wb.x + xb.y * wb.y + xb.z * wb.z + xb.w * wb.w;
      }
      float s = s0 + s1;
      s += __shfl_xor(s, 1, 4);
      s += __shfl_xor(s, 2, 4);
      if (s4 == 0) glr[n] = s;
    }
    {  // 16 tail pairs (u>=1): 16 threads per pair
      const int p = tid >> 4, s16 = tid & 15;
      int u, n; pair_un(p, u, n);
      const float4* xw = (const float4*)(x + ((size_t)b * SEQ_L + u) * DMODEL);
      const float4* wr = (const float4*)(W_B + (size_t)n * DMODEL);
      float s = 0.f;
#pragma unroll
      for (int k = 0; k < 16; ++k) {
        const float4 xv = xw[k * 16 + s16], wv = wr[k * 16 + s16];
        s += xv.x * wv.x + xv.y * wv.y + xv.z * wv.z + xv.w * wv.w;
      }
#pragma unroll
      for (int off = 8; off; off >>= 1) s += __shfl_xor(s, off, 16);
      if (s16 == 0) glr[NSTATE + p] = s;
    }
    __syncthreads();
    if (tid < NGL) {
      float v;
      if (tid < NSTATE) {
        v = glr[tid] + b_B[tid];  // A^0 = 1
      } else {
        int u, n; pair_un(tid - NSTATE, u, n);
        v = (glr[tid] + b_B[n]) * __expf((float)u * log_A[n]);
      }
      gls[tid] = v;
      __hip_atomic_store(glp + tid, v, __ATOMIC_RELAXED, __HIP_MEMORY_SCOPE_AGENT);
    }
    __syncthreads();
    if (tid == 0)
      __hip_atomic_store(mg, (uint64_t)MAGIC, __ATOMIC_RELEASE, __HIP_MEMORY_SCOPE_AGENT);
    __syncthreads();
  } else {
    // ---- Consumer: spin on magic (~1us), then fetch gl coherently ----
    if (tid == 0) {
      while (__hip_atomic_load(mg, __ATOMIC_ACQUIRE, __HIP_MEMORY_SCOPE_AGENT) !=
             (uint64_t)MAGIC)
        __builtin_amdgcn_s_sleep(2);
    }
    __syncthreads();
    if (tid < NGL)
      gls[tid] = __hip_atomic_load(glp + tid, __ATOMIC_RELAXED, __HIP_MEMORY_SCOPE_AGENT);
    __syncthreads();
  }

  // ---- Per-thread K taps from gls + C (C is read-only: no staleness) ----
  float2 K2[T_TAP];
  float2 c0[6];
  {
#pragma unroll
    for (int u = 1; u < T_TAP; ++u) K2[u] = make_float2(0.f, 0.f);
    float kx = 0.f, ky = 0.f;
#pragma unroll
    for (int n = 0; n < 6; ++n) {  // keep rows 0..5 for the tail pairs
      const float2 cv = *(const float2*)(C + (size_t)n * DMODEL + 2 * m2);
      c0[n] = cv;
      kx += gls[n] * cv.x;
      ky += gls[n] * cv.y;
    }
#pragma unroll 8
    for (int n = 6; n < NSTATE; ++n) {
      const float2 cv = *(const float2*)(C + (size_t)n * DMODEL + 2 * m2);
      kx += gls[n] * cv.x;
      ky += gls[n] * cv.y;
    }
    K2[0] = make_float2(kx, ky);
    constexpr int UT[NPAIR] = {1,1,1,1,1,1, 2,2,2, 3,3, 4,4, 5, 6, 7};
    constexpr int NT[NPAIR] = {0,1,2,3,4,5, 0,1,2, 0,1, 0,1, 0, 0, 0};
#pragma unroll
    for (int p = 0; p < NPAIR; ++p) {
      const float g = gls[NSTATE + p];
      K2[UT[p]].x += g * c0[NT[p]].x;
      K2[UT[p]].y += g * c0[NT[p]].y;
    }
  }

  // ---- Conv: y[t] = D*x[t] + sum_u K[u]*x[t-u] (R3 structure, unchanged) ----
  float2* y2 = (float2*)(y + (size_t)b * SEQ_L * DMODEL) + m2;
#pragma unroll
  for (int j = 0; j < TT; ++j) {
    const float2 xc = xr[HALO + j];
    float ax = d2.x * xc.x;
    float ay = d2.y * xc.y;
#pragma unroll
    for (int u = 0; u < T_TAP; ++u) {
      const float2 xv = xr[HALO + j - u];
      ax += K2[u].x * xv.x;
      ay += K2[u].y * xv.y;
    }
    y2[(size_t)(t0 + j) * S2] = make_float2(ax, ay);
  }
}

// ---------------------------------------------------------------------------
extern "C" void kernel_launch(void* const* d_in, const int* in_sizes, int n_in,
                              void* d_out, int out_size, void* d_ws, size_t ws_size,
                              hipStream_t stream) {
  const float* x     = (const float*)d_in[0];
  const float* W_B   = (const float*)d_in[1];
  const float* b_B   = (const float*)d_in[2];
  const float* C     = (const float*)d_in[3];
  const float* D     = (const float*)d_in[4];
  const float* log_A = (const float*)d_in[5];
  float* y = (float*)d_out;
  float* ws = (float*)d_ws;  // gl[4][128] + magic words: < 8 KB used

  dim3 g(SEQ_L / TT, DMODEL / 512, BATCH);
  s4_one<<<g, 256, 0, stream>>>(x, W_B, b_B, C, D, log_A, y, ws);
}

// Round 6
// 102.876 us; speedup vs baseline: 2.2058x; 2.2058x over previous
//
#include <hip/hip_runtime.h>

// Problem: B=4, L=2048, DM=1024, N=64.
//   y[b,t,m] = D[m]*x[b,t,m] + sum_u K[b,u,m]*x[b,t-u,m]
//   K[b,u,m] = sum_n C[n,m] * A_n^u * (x[b,u,:]·W_B[n,:] + b_B[n]), A_n = e^{0.1-(3n+1)}
// A_n^u decays so fast that taps u>=8 are < 1e-10 -> 8-tap causal FIR.
//
// R4 post-mortem (137us single-kernel disaster): 504 blocks polling an
// AGENT-scope atomic serialized the coherence point (VALUBusy 1.5%, HBM 5%),
// and the compiler sank the register-prefetched x-window below the divergent
// spin region (VGPR 60). Lesson: no cross-block handshakes; two launches.
//
// R5/R6 = R3 (verified 103.2us) + conv widened to 16B/lane (float4 channels):
// the 6.29 TB/s copy ceiling is measured at 16B/lane; 8B/lane issues 2x the
// VMEM instructions for the same bytes. (R5 bench was an infra failure —
// container died before running; this is an unchanged resubmit.)

#define BATCH 4
#define SEQ_L 2048
#define DMODEL 1024
#define NSTATE 64
#define T_TAP 8
#define HALO (T_TAP - 1)  // 7
#define TT 16             // t-outputs per thread in conv

// ---------------------------------------------------------------------------
// Kernel A (verbatim from R3, verified): K[b,u,m] for u<8.
// grid (T_TAP, BATCH) = 32 blocks x 1024 thr.
// ---------------------------------------------------------------------------
__global__ __launch_bounds__(1024) void s4_build_k(
    const float* __restrict__ x, const float* __restrict__ W_B,
    const float* __restrict__ b_B, const float* __restrict__ C,
    const float* __restrict__ log_A, float* __restrict__ K) {
  const int u = blockIdx.x;
  const int b = blockIdx.y;
  const int tid = threadIdx.x;

  __shared__ float glr[NSTATE];
  __shared__ float gl[NSTATE];

  const int n = tid >> 4;
  const int sub = tid & 15;
  const float4* xr = (const float4*)(x + ((size_t)b * SEQ_L + u) * DMODEL);
  const float4* wr = (const float4*)(W_B + (size_t)n * DMODEL);
  float s = 0.f;
#pragma unroll
  for (int c = 0; c < 16; ++c) {
    const float4 xv = xr[sub + 16 * c];
    const float4 wv = wr[sub + 16 * c];
    s += xv.x * wv.x + xv.y * wv.y + xv.z * wv.z + xv.w * wv.w;
  }
#pragma unroll
  for (int off = 8; off; off >>= 1) s += __shfl_xor(s, off, 16);
  if (sub == 0) glr[n] = s;
  __syncthreads();

  if (tid < NSTATE)
    gl[tid] = (glr[tid] + b_B[tid]) * __expf((float)u * log_A[tid]);
  __syncthreads();

  float a0 = 0.f, a1 = 0.f, a2 = 0.f, a3 = 0.f;
#pragma unroll
  for (int nn = 0; nn < NSTATE; nn += 4) {
    a0 += gl[nn + 0] * C[(size_t)(nn + 0) * DMODEL + tid];
    a1 += gl[nn + 1] * C[(size_t)(nn + 1) * DMODEL + tid];
    a2 += gl[nn + 2] * C[(size_t)(nn + 2) * DMODEL + tid];
    a3 += gl[nn + 3] * C[(size_t)(nn + 3) * DMODEL + tid];
  }
  K[((size_t)b * T_TAP + u) * DMODEL + tid] = (a0 + a1) + (a2 + a3);
}

// ---------------------------------------------------------------------------
// Kernel B: streaming 8-tap FIR, no LDS, no barriers, 16B/lane.
// Thread = 4 consecutive channels (float4) x TT=16 outputs.
// xr[23] float4 window in registers (static idx); ~145 VGPR, no spill
// (no launch_bounds min -> allocator free up to 256).
// grid (L/TT=128, B=4) = 512 blocks x 256 thr; 256 thr x 4ch = full DM row.
// Traffic: x 33MB (halo re-reads absorbed by L3) + y 33.6MB -> ~10.5us floor.
// ---------------------------------------------------------------------------
__global__ __launch_bounds__(256) void s4_conv(
    const float* __restrict__ x, const float* __restrict__ K,
    const float* __restrict__ D, float* __restrict__ y) {
  const int tid = threadIdx.x;          // float4-channel index, 0..255
  const int t0 = blockIdx.x * TT;
  const int b = blockIdx.y;
  const int S4 = DMODEL / 4;            // float4 row stride (256)

  // K taps + D for this channel quad (coalesced; K is L2/L3-hot, 128 KB)
  float4 K4[T_TAP];
  const float4* Kp = (const float4*)(K + (size_t)b * T_TAP * DMODEL) + tid;
#pragma unroll
  for (int u = 0; u < T_TAP; ++u) K4[u] = Kp[(size_t)u * S4];
  const float4 d4 = ((const float4*)D)[tid];

  // x window [t0-7 .. t0+TT-1] for this channel quad -> registers.
  const float4* x4 = (const float4*)(x + (size_t)b * SEQ_L * DMODEL) + tid;
  float4 xr[TT + HALO];
#pragma unroll
  for (int i = 0; i < HALO; ++i) {
    const int t = t0 - HALO + i;
    xr[i] = (t >= 0) ? x4[(size_t)t * S4] : make_float4(0.f, 0.f, 0.f, 0.f);
  }
#pragma unroll
  for (int j = 0; j < TT; ++j) xr[HALO + j] = x4[(size_t)(t0 + j) * S4];

  // y[t] = D*x[t] + sum_u K[u]*x[t-u]
  float4* y4 = (float4*)(y + (size_t)b * SEQ_L * DMODEL) + tid;
#pragma unroll
  for (int j = 0; j < TT; ++j) {
    const float4 xc = xr[HALO + j];
    float ax = d4.x * xc.x, ay = d4.y * xc.y, az = d4.z * xc.z, aw = d4.w * xc.w;
#pragma unroll
    for (int u = 0; u < T_TAP; ++u) {
      const float4 xv = xr[HALO + j - u];
      ax += K4[u].x * xv.x;
      ay += K4[u].y * xv.y;
      az += K4[u].z * xv.z;
      aw += K4[u].w * xv.w;
    }
    y4[(size_t)(t0 + j) * S4] = make_float4(ax, ay, az, aw);
  }
}

// ---------------------------------------------------------------------------
extern "C" void kernel_launch(void* const* d_in, const int* in_sizes, int n_in,
                              void* d_out, int out_size, void* d_ws, size_t ws_size,
                              hipStream_t stream) {
  const float* x     = (const float*)d_in[0];
  const float* W_B   = (const float*)d_in[1];
  const float* b_B   = (const float*)d_in[2];
  const float* C     = (const float*)d_in[3];
  const float* D     = (const float*)d_in[4];
  const float* log_A = (const float*)d_in[5];
  float* y = (float*)d_out;
  float* K = (float*)d_ws;  // BATCH * T_TAP * DMODEL * 4 = 128 KB

  dim3 gA(T_TAP, BATCH);
  s4_build_k<<<gA, 1024, 0, stream>>>(x, W_B, b_B, C, log_A, K);

  dim3 gB(SEQ_L / TT, BATCH);
  s4_conv<<<gB, 256, 0, stream>>>(x, K, D, y);
}